// Round 2
// baseline (173.385 us; speedup 1.0000x reference)
//
#include <hip/hip_runtime.h>
#include <cstdint>

#define CH 192
#define HW 65536
#define PN 64           // pixels per workgroup
#define PITCH 196       // LDS row pitch in bf16 elems (mult of 4 -> 8B-aligned b64 reads; 4-way-max write conflicts)
#define KB 6            // K blocks (192/32)

#define GAMMA_BOUND 3.814697265625e-06f            // 2^-18
#define PEDESTAL    1.4551915228366852e-11f        // 2^-36
#define BETA_BOUND  1.0000072759550125e-03f        // sqrt(1e-6 + 2^-36)

typedef __attribute__((ext_vector_type(8))) __bf16 bf16x8;
typedef __attribute__((ext_vector_type(4))) __bf16 bf16x4;
typedef __attribute__((ext_vector_type(4))) float  f32x4;

__device__ __forceinline__ ushort f2bf(float f) {
    union { float f; uint32_t u; } v; v.f = f;
    uint32_t u = v.u;
    return (ushort)((u + 0x7FFFu + ((u >> 16) & 1u)) >> 16);  // RNE
}
__device__ __forceinline__ float bf2f(ushort h) {
    union { uint32_t u; float f; } v; v.u = ((uint32_t)h) << 16;
    return v.f;
}

// ---- prep: reparam params, convert G to bf16, into workspace ----
__global__ __launch_bounds__(256) void gsdn_prep(
    const float* __restrict__ beta, const float* __restrict__ gamma,
    const float* __restrict__ beta2, const float* __restrict__ gamma2,
    ushort* __restrict__ g2bf, ushort* __restrict__ g1bf,
    float* __restrict__ b2r, float* __restrict__ b1r)
{
    int i = blockIdx.x * 256 + threadIdx.x;
    if (i < CH * CH) {
        float g = fmaxf(gamma2[i], GAMMA_BOUND);
        g2bf[i] = f2bf(g * g - PEDESTAL);
        float h = fmaxf(gamma[i], GAMMA_BOUND);
        g1bf[i] = f2bf(h * h - PEDESTAL);
    }
    if (i < CH) {
        float b = fmaxf(beta2[i], BETA_BOUND);
        b2r[i] = b * b - PEDESTAL;
        float a = fmaxf(beta[i], BETA_BOUND);
        b1r[i] = a * a - PEDESTAL;
    }
}

__device__ __forceinline__ bf16x8 ldsfrag(const ushort* Xs, int n, int k0) {
    union { bf16x8 v; struct { bf16x4 lo; bf16x4 hi; } s; } u;
    u.s.lo = *(const bf16x4*)&Xs[n * PITCH + k0];
    u.s.hi = *(const bf16x4*)&Xs[n * PITCH + k0 + 4];
    return u.v;
}

// ---- main fused kernel ----
__global__ __launch_bounds__(256, 4) void gsdn_main(
    const float* __restrict__ X,
    const ushort* __restrict__ g2bf, const ushort* __restrict__ g1bf,
    const float* __restrict__ b2r, const float* __restrict__ b1r,
    float* __restrict__ Y)
{
    __shared__ ushort Xs[PN * PITCH];   // 25088 B: v tile first, then x*x tile (in-place)

    const int tid  = threadIdx.x;
    const int wave = tid >> 6;
    const int lane = tid & 63;

    const int wg = blockIdx.x;
    const int b  = wg >> 10;                 // 1024 WGs per batch image
    const int n0 = (wg & 1023) * PN;

    const float* Xb = X + (size_t)b * CH * HW + n0;
    float*       Yb = Y + (size_t)b * CH * HW + n0;

    // ---- stage X tile -> LDS (bf16, transposed [n][c]), float4 global loads ----
    {
        const int g  = tid & 15;             // pixel quad (pixels 4g..4g+3)
        const int c0 = tid >> 4;             // 0..15
        #pragma unroll
        for (int j = 0; j < 12; ++j) {
            const int c = c0 + 16 * j;
            const float4 v = *(const float4*)&Xb[(size_t)c * HW + 4 * g];
            Xs[(4 * g + 0) * PITCH + c] = f2bf(v.x);
            Xs[(4 * g + 1) * PITCH + c] = f2bf(v.y);
            Xs[(4 * g + 2) * PITCH + c] = f2bf(v.z);
            Xs[(4 * g + 3) * PITCH + c] = f2bf(v.w);
        }
    }
    __syncthreads();

    const int lm = lane & 15;       // pixel-in-block / D column
    const int lh = lane >> 4;       // 0..3 (k block / D row group)

    // ---- GEMM1: m = G2 @ v ----
    f32x4 acc[3][4];
    #pragma unroll
    for (int o = 0; o < 3; ++o)
        #pragma unroll
        for (int nb = 0; nb < 4; ++nb)
            acc[o][nb] = (f32x4){0.f, 0.f, 0.f, 0.f};

    #pragma unroll
    for (int kb = 0; kb < KB; ++kb) {
        bf16x8 bfr[4];
        #pragma unroll
        for (int nb = 0; nb < 4; ++nb)
            bfr[nb] = ldsfrag(Xs, nb * 16 + lm, kb * 32 + 8 * lh);
        #pragma unroll
        for (int o = 0; o < 3; ++o) {
            const int orow = (3 * wave + o) * 16 + lm;
            bf16x8 afr = *(const bf16x8*)(g2bf + orow * CH + kb * 32 + 8 * lh);
            #pragma unroll
            for (int nb = 0; nb < 4; ++nb)
                acc[o][nb] = __builtin_amdgcn_mfma_f32_16x16x32_bf16(afr, bfr[nb], acc[o][nb], 0, 0, 0);
        }
    }
    __syncthreads();   // GEMM1 reads of Xs complete before in-place overwrite

    // ---- x = v - (m + b2); Xs <- (x*x) bf16 in place; keep x in acc ----
    #pragma unroll
    for (int o = 0; o < 3; ++o) {
        const int cb = (3 * wave + o) * 16 + 4 * lh;
        const float4 b2v = *(const float4*)(b2r + cb);
        #pragma unroll
        for (int nb = 0; nb < 4; ++nb) {
            const int n = nb * 16 + lm;
            ushort4 vv = *(const ushort4*)&Xs[n * PITCH + cb];
            float x0 = bf2f(vv.x) - (acc[o][nb][0] + b2v.x);
            float x1 = bf2f(vv.y) - (acc[o][nb][1] + b2v.y);
            float x2 = bf2f(vv.z) - (acc[o][nb][2] + b2v.z);
            float x3 = bf2f(vv.w) - (acc[o][nb][3] + b2v.w);
            acc[o][nb][0] = x0; acc[o][nb][1] = x1;
            acc[o][nb][2] = x2; acc[o][nb][3] = x3;
            ushort4 q;
            q.x = f2bf(x0 * x0); q.y = f2bf(x1 * x1);
            q.z = f2bf(x2 * x2); q.w = f2bf(x3 * x3);
            *(ushort4*)&Xs[n * PITCH + cb] = q;
        }
    }
    __syncthreads();

    // ---- GEMM2: S = G1 @ (x*x) ----
    f32x4 acs[3][4];
    #pragma unroll
    for (int o = 0; o < 3; ++o)
        #pragma unroll
        for (int nb = 0; nb < 4; ++nb)
            acs[o][nb] = (f32x4){0.f, 0.f, 0.f, 0.f};

    #pragma unroll
    for (int kb = 0; kb < KB; ++kb) {
        bf16x8 bfr[4];
        #pragma unroll
        for (int nb = 0; nb < 4; ++nb)
            bfr[nb] = ldsfrag(Xs, nb * 16 + lm, kb * 32 + 8 * lh);
        #pragma unroll
        for (int o = 0; o < 3; ++o) {
            const int orow = (3 * wave + o) * 16 + lm;
            bf16x8 afr = *(const bf16x8*)(g1bf + orow * CH + kb * 32 + 8 * lh);
            #pragma unroll
            for (int nb = 0; nb < 4; ++nb)
                acs[o][nb] = __builtin_amdgcn_mfma_f32_16x16x32_bf16(afr, bfr[nb], acs[o][nb], 0, 0, 0);
        }
    }

    // ---- out = x * rsqrt(S + b1) ----
    #pragma unroll
    for (int o = 0; o < 3; ++o) {
        const int cb = (3 * wave + o) * 16 + 4 * lh;
        const float4 b1v = *(const float4*)(b1r + cb);
        #pragma unroll
        for (int nb = 0; nb < 4; ++nb) {
            const int n = nb * 16 + lm;
            float r0 = rsqrtf(acs[o][nb][0] + b1v.x);
            float r1 = rsqrtf(acs[o][nb][1] + b1v.y);
            float r2 = rsqrtf(acs[o][nb][2] + b1v.z);
            float r3 = rsqrtf(acs[o][nb][3] + b1v.w);
            Yb[(size_t)(cb + 0) * HW + n] = acc[o][nb][0] * r0;
            Yb[(size_t)(cb + 1) * HW + n] = acc[o][nb][1] * r1;
            Yb[(size_t)(cb + 2) * HW + n] = acc[o][nb][2] * r2;
            Yb[(size_t)(cb + 3) * HW + n] = acc[o][nb][3] * r3;
        }
    }
}

extern "C" void kernel_launch(void* const* d_in, const int* in_sizes, int n_in,
                              void* d_out, int out_size, void* d_ws, size_t ws_size,
                              hipStream_t stream) {
    const float* X      = (const float*)d_in[0];
    const float* beta   = (const float*)d_in[1];
    const float* gamma  = (const float*)d_in[2];
    const float* beta2  = (const float*)d_in[3];
    const float* gamma2 = (const float*)d_in[4];
    float* Y = (float*)d_out;

    ushort* g2bf = (ushort*)d_ws;
    ushort* g1bf = g2bf + CH * CH;
    float*  b2r  = (float*)(g1bf + CH * CH);
    float*  b1r  = b2r + CH;

    hipLaunchKernelGGL(gsdn_prep, dim3((CH * CH + 255) / 256), dim3(256), 0, stream,
                       beta, gamma, beta2, gamma2, g2bf, g1bf, b2r, b1r);
    hipLaunchKernelGGL(gsdn_main, dim3(4 * (HW / PN)), dim3(256), 0, stream,
                       X, g2bf, g1bf, b2r, b1r, Y);
}

// Round 3
// 155.097 us; speedup vs baseline: 1.1179x; 1.1179x over previous
//
#include <hip/hip_runtime.h>
#include <cstdint>

#define CH 192
#define HW 65536
#define PN 64           // pixels per tile
#define PITCH 196       // LDS row pitch in bf16 elems
#define KB 6            // K blocks (192/32)
#define NWG 768         // persistent workgroups (3 per CU)
#define NTILE 4096      // total tiles (4 * 65536 / 64)

#define GAMMA_BOUND 3.814697265625e-06f            // 2^-18
#define PEDESTAL    1.4551915228366852e-11f        // 2^-36
#define BETA_BOUND  1.0000072759550125e-03f        // sqrt(1e-6 + 2^-36)

typedef __attribute__((ext_vector_type(8))) __bf16 bf16x8;
typedef __attribute__((ext_vector_type(4))) __bf16 bf16x4;
typedef __attribute__((ext_vector_type(4))) float  f32x4;

// barrier that does NOT drain vmcnt (keeps prefetch loads in flight);
// memory-clobber sandwich stops the compiler moving LDS ops across it.
#define BAR_LGKM() do {                                        \
    asm volatile("s_waitcnt lgkmcnt(0)" ::: "memory");          \
    __builtin_amdgcn_s_barrier();                               \
    asm volatile("" ::: "memory");                              \
} while (0)

__device__ __forceinline__ ushort f2bf(float f) {
    union { float f; uint32_t u; } v; v.f = f;
    uint32_t u = v.u;
    return (ushort)((u + 0x7FFFu + ((u >> 16) & 1u)) >> 16);  // RNE
}
__device__ __forceinline__ float bf2f(ushort h) {
    union { uint32_t u; float f; } v; v.u = ((uint32_t)h) << 16;
    return v.f;
}

// ---- prep: reparam params, convert G to bf16, into workspace ----
__global__ __launch_bounds__(256) void gsdn_prep(
    const float* __restrict__ beta, const float* __restrict__ gamma,
    const float* __restrict__ beta2, const float* __restrict__ gamma2,
    ushort* __restrict__ g2bf, ushort* __restrict__ g1bf,
    float* __restrict__ b2r, float* __restrict__ b1r)
{
    int i = blockIdx.x * 256 + threadIdx.x;
    if (i < CH * CH) {
        float g = fmaxf(gamma2[i], GAMMA_BOUND);
        g2bf[i] = f2bf(g * g - PEDESTAL);
        float h = fmaxf(gamma[i], GAMMA_BOUND);
        g1bf[i] = f2bf(h * h - PEDESTAL);
    }
    if (i < CH) {
        float b = fmaxf(beta2[i], BETA_BOUND);
        b2r[i] = b * b - PEDESTAL;
        float a = fmaxf(beta[i], BETA_BOUND);
        b1r[i] = a * a - PEDESTAL;
    }
}

__device__ __forceinline__ bf16x8 ldsfrag(const ushort* S, int n, int k0) {
    union { bf16x8 v; struct { bf16x4 lo; bf16x4 hi; } s; } u;
    u.s.lo = *(const bf16x4*)&S[n * PITCH + k0];
    u.s.hi = *(const bf16x4*)&S[n * PITCH + k0 + 4];
    return u.v;
}

// ---- main fused kernel: persistent WGs, software-pipelined tiles ----
__global__ __launch_bounds__(256, 3) void gsdn_main(
    const float* __restrict__ X,
    const ushort* __restrict__ g2bf, const ushort* __restrict__ g1bf,
    const float* __restrict__ b2r, const float* __restrict__ b1r,
    float* __restrict__ Y)
{
    __shared__ ushort Xs[PN * PITCH];   // v tile -> x tile (in place), bf16 [n][c]
    __shared__ ushort Qs[PN * PITCH];   // x*x tile, bf16 [n][c]

    const int tid  = threadIdx.x;
    const int wave = tid >> 6;
    const int lane = tid & 63;
    const int lm   = lane & 15;     // pixel-in-block / D column
    const int lh   = lane >> 4;     // 0..3
    const int g    = tid & 15;      // pixel quad (pixels 4g..4g+3)
    const int c0   = tid >> 4;      // 0..15

    const int wg = blockIdx.x;
    const int ntiles = (wg < (NTILE - 5 * NWG)) ? 6 : 5;

    // prologue: prefetch tile 0 into registers
    float4 R[12];
    {
        const int t = wg;
        const float* Xb = X + ((size_t)(t >> 10) * CH * HW) + (size_t)(t & 1023) * PN;
        #pragma unroll
        for (int j = 0; j < 12; ++j)
            R[j] = *(const float4*)&Xb[(size_t)(c0 + 16 * j) * HW + 4 * g];
    }

    for (int it = 0; it < ntiles; ++it) {
        // ---- writeback staged tile -> LDS (bf16, transposed [n][c]) ----
        #pragma unroll
        for (int j = 0; j < 12; ++j) {
            const int c = c0 + 16 * j;
            Xs[(4 * g + 0) * PITCH + c] = f2bf(R[j].x);
            Xs[(4 * g + 1) * PITCH + c] = f2bf(R[j].y);
            Xs[(4 * g + 2) * PITCH + c] = f2bf(R[j].z);
            Xs[(4 * g + 3) * PITCH + c] = f2bf(R[j].w);
        }
        BAR_LGKM();   // B1: stage visible

        // ---- issue next tile's loads (stay in flight across compute) ----
        if (it + 1 < ntiles) {
            const int t = wg + (it + 1) * NWG;
            const float* Xb = X + ((size_t)(t >> 10) * CH * HW) + (size_t)(t & 1023) * PN;
            #pragma unroll
            for (int j = 0; j < 12; ++j)
                R[j] = *(const float4*)&Xb[(size_t)(c0 + 16 * j) * HW + 4 * g];
        }

        const int t0 = wg + it * NWG;
        float* Yb = Y + ((size_t)(t0 >> 10) * CH * HW) + (size_t)(t0 & 1023) * PN;

        // ---- GEMM1: m = G2 @ v ----
        f32x4 acc[3][4];
        #pragma unroll
        for (int o = 0; o < 3; ++o)
            #pragma unroll
            for (int nb = 0; nb < 4; ++nb)
                acc[o][nb] = (f32x4){0.f, 0.f, 0.f, 0.f};

        #pragma unroll
        for (int kb = 0; kb < KB; ++kb) {
            bf16x8 bfr[4];
            #pragma unroll
            for (int nb = 0; nb < 4; ++nb)
                bfr[nb] = ldsfrag(Xs, nb * 16 + lm, kb * 32 + 8 * lh);
            #pragma unroll
            for (int o = 0; o < 3; ++o) {
                const int orow = (3 * wave + o) * 16 + lm;
                bf16x8 afr = *(const bf16x8*)(g2bf + orow * CH + kb * 32 + 8 * lh);
                #pragma unroll
                for (int nb = 0; nb < 4; ++nb)
                    acc[o][nb] = __builtin_amdgcn_mfma_f32_16x16x32_bf16(afr, bfr[nb], acc[o][nb], 0, 0, 0);
            }
        }
        BAR_LGKM();   // B2: all GEMM1 reads of Xs done before in-place overwrite

        // ---- x = v - (m + b2); Xs <- x (bf16), Qs <- x*x (bf16) ----
        #pragma unroll
        for (int o = 0; o < 3; ++o) {
            const int cb = (3 * wave + o) * 16 + 4 * lh;
            const float4 b2v = *(const float4*)(b2r + cb);
            #pragma unroll
            for (int nb = 0; nb < 4; ++nb) {
                const int n = nb * 16 + lm;
                ushort4 vv = *(const ushort4*)&Xs[n * PITCH + cb];
                float x0 = bf2f(vv.x) - (acc[o][nb][0] + b2v.x);
                float x1 = bf2f(vv.y) - (acc[o][nb][1] + b2v.y);
                float x2 = bf2f(vv.z) - (acc[o][nb][2] + b2v.z);
                float x3 = bf2f(vv.w) - (acc[o][nb][3] + b2v.w);
                ushort4 xw;
                xw.x = f2bf(x0); xw.y = f2bf(x1); xw.z = f2bf(x2); xw.w = f2bf(x3);
                *(ushort4*)&Xs[n * PITCH + cb] = xw;
                ushort4 q;
                q.x = f2bf(x0 * x0); q.y = f2bf(x1 * x1);
                q.z = f2bf(x2 * x2); q.w = f2bf(x3 * x3);
                *(ushort4*)&Qs[n * PITCH + cb] = q;
            }
        }
        BAR_LGKM();   // B3: x / x^2 visible

        // ---- GEMM2: S = G1 @ (x*x), reusing acc registers ----
        #pragma unroll
        for (int o = 0; o < 3; ++o)
            #pragma unroll
            for (int nb = 0; nb < 4; ++nb)
                acc[o][nb] = (f32x4){0.f, 0.f, 0.f, 0.f};

        #pragma unroll
        for (int kb = 0; kb < KB; ++kb) {
            bf16x8 bfr[4];
            #pragma unroll
            for (int nb = 0; nb < 4; ++nb)
                bfr[nb] = ldsfrag(Qs, nb * 16 + lm, kb * 32 + 8 * lh);
            #pragma unroll
            for (int o = 0; o < 3; ++o) {
                const int orow = (3 * wave + o) * 16 + lm;
                bf16x8 afr = *(const bf16x8*)(g1bf + orow * CH + kb * 32 + 8 * lh);
                #pragma unroll
                for (int nb = 0; nb < 4; ++nb)
                    acc[o][nb] = __builtin_amdgcn_mfma_f32_16x16x32_bf16(afr, bfr[nb], acc[o][nb], 0, 0, 0);
            }
        }

        // ---- out = x * rsqrt(S + b1) ----
        #pragma unroll
        for (int o = 0; o < 3; ++o) {
            const int cb = (3 * wave + o) * 16 + 4 * lh;
            const float4 b1v = *(const float4*)(b1r + cb);
            #pragma unroll
            for (int nb = 0; nb < 4; ++nb) {
                const int n = nb * 16 + lm;
                ushort4 xv = *(const ushort4*)&Xs[n * PITCH + cb];
                float r0 = rsqrtf(acc[o][nb][0] + b1v.x);
                float r1 = rsqrtf(acc[o][nb][1] + b1v.y);
                float r2 = rsqrtf(acc[o][nb][2] + b1v.z);
                float r3 = rsqrtf(acc[o][nb][3] + b1v.w);
                Yb[(size_t)(cb + 0) * HW + n] = bf2f(xv.x) * r0;
                Yb[(size_t)(cb + 1) * HW + n] = bf2f(xv.y) * r1;
                Yb[(size_t)(cb + 2) * HW + n] = bf2f(xv.z) * r2;
                Yb[(size_t)(cb + 3) * HW + n] = bf2f(xv.w) * r3;
            }
        }
        BAR_LGKM();   // B4: epilogue LDS reads done before next stage overwrites Xs
    }
}

extern "C" void kernel_launch(void* const* d_in, const int* in_sizes, int n_in,
                              void* d_out, int out_size, void* d_ws, size_t ws_size,
                              hipStream_t stream) {
    const float* X      = (const float*)d_in[0];
    const float* beta   = (const float*)d_in[1];
    const float* gamma  = (const float*)d_in[2];
    const float* beta2  = (const float*)d_in[3];
    const float* gamma2 = (const float*)d_in[4];
    float* Y = (float*)d_out;

    ushort* g2bf = (ushort*)d_ws;
    ushort* g1bf = g2bf + CH * CH;
    float*  b2r  = (float*)(g1bf + CH * CH);
    float*  b1r  = b2r + CH;

    hipLaunchKernelGGL(gsdn_prep, dim3((CH * CH + 255) / 256), dim3(256), 0, stream,
                       beta, gamma, beta2, gamma2, g2bf, g1bf, b2r, b1r);
    hipLaunchKernelGGL(gsdn_main, dim3(NWG), dim3(256), 0, stream,
                       X, g2bf, g1bf, b2r, b1r, Y);
}

// Round 4
// 154.145 us; speedup vs baseline: 1.1248x; 1.0062x over previous
//
#include <hip/hip_runtime.h>
#include <cstdint>

#define CH 192
#define HW 65536
#define PN 48           // pixels per tile
#define PITCH 196       // LDS row pitch in bf16 elems (8B-aligned b64 reads)
#define KB 6            // K blocks (192/32)
#define NTPI 1366       // tiles per image: 1365 full + 1 tail of 16 px

#define GAMMA_BOUND 3.814697265625e-06f            // 2^-18
#define PEDESTAL    1.4551915228366852e-11f        // 2^-36
#define BETA_BOUND  1.0000072759550125e-03f        // sqrt(1e-6 + 2^-36)

typedef __attribute__((ext_vector_type(8))) __bf16 bf16x8;
typedef __attribute__((ext_vector_type(4))) __bf16 bf16x4;
typedef __attribute__((ext_vector_type(4))) float  f32x4;

__device__ __forceinline__ ushort f2bf(float f) {
    union { float f; uint32_t u; } v; v.f = f;
    uint32_t u = v.u;
    return (ushort)((u + 0x7FFFu + ((u >> 16) & 1u)) >> 16);  // RNE
}
__device__ __forceinline__ float bf2f(ushort h) {
    union { uint32_t u; float f; } v; v.u = ((uint32_t)h) << 16;
    return v.f;
}
__device__ __forceinline__ float rsq(float x) {
    float r; asm("v_rsq_f32 %0, %1" : "=v"(r) : "v"(x)); return r;
}

// ---- prep: reparam params; store G2/G1 in MFMA-fragment order ----
// g2sw layout: frag (o,kb) at offset ((o*KB+kb)*64 + lane)*8, holding
// G2[o*16 + (lane&15)][kb*32 + 8*(lane>>4) + j], j=0..7  -> A-frag loads
// become lane*16B contiguous (1 KiB per wave instruction).
__global__ __launch_bounds__(256) void gsdn_prep(
    const float* __restrict__ beta, const float* __restrict__ gamma,
    const float* __restrict__ beta2, const float* __restrict__ gamma2,
    ushort* __restrict__ g2sw, ushort* __restrict__ g1sw,
    float* __restrict__ b2r, float* __restrict__ b1r)
{
    int t = blockIdx.x * 256 + threadIdx.x;
    if (t < 12 * KB * 64) {
        const int o    = t / (KB * 64);
        const int r    = t - o * (KB * 64);
        const int kb   = r >> 6;
        const int lane = r & 63;
        const int row  = o * 16 + (lane & 15);
        const int col0 = kb * 32 + 8 * (lane >> 4);
        ushort w2[8], w1[8];
        #pragma unroll
        for (int j = 0; j < 8; ++j) {
            float g = fmaxf(gamma2[row * CH + col0 + j], GAMMA_BOUND);
            w2[j] = f2bf(g * g - PEDESTAL);
            float h = fmaxf(gamma[row * CH + col0 + j], GAMMA_BOUND);
            w1[j] = f2bf(h * h - PEDESTAL);
        }
        #pragma unroll
        for (int j = 0; j < 8; ++j) { g2sw[t * 8 + j] = w2[j]; g1sw[t * 8 + j] = w1[j]; }
    }
    if (t < CH) {
        float b = fmaxf(beta2[t], BETA_BOUND);
        b2r[t] = b * b - PEDESTAL;
        float a = fmaxf(beta[t], BETA_BOUND);
        b1r[t] = a * a - PEDESTAL;
    }
}

__device__ __forceinline__ bf16x8 ldsfrag(const ushort* S, int n, int k0) {
    union { bf16x8 v; struct { bf16x4 lo; bf16x4 hi; } s; } u;
    u.s.lo = *(const bf16x4*)&S[n * PITCH + k0];
    u.s.hi = *(const bf16x4*)&S[n * PITCH + k0 + 4];
    return u.v;
}

// ---- main fused kernel: 1 tile per WG, 4 WGs/CU ----
__global__ __launch_bounds__(256, 4) void gsdn_main(
    const float* __restrict__ X,
    const ushort* __restrict__ g2sw, const ushort* __restrict__ g1sw,
    const float* __restrict__ b2r, const float* __restrict__ b1r,
    float* __restrict__ Y)
{
    __shared__ ushort Xs[PN * PITCH];   // v tile -> x tile (in place), bf16 [n][c]
    __shared__ ushort Qs[PN * PITCH];   // x*x tile, bf16 [n][c]

    const int tid  = threadIdx.x;
    const int wave = tid >> 6;
    const int lane = tid & 63;
    const int lm   = lane & 15;
    const int lh   = lane >> 4;

    const int base = blockIdx.x * PN;
    const int npx  = (base + PN <= HW) ? PN : (HW - base);   // 48 or 16
    const float* Xb = X + (size_t)blockIdx.y * CH * HW;
    float*       Yb = Y + (size_t)blockIdx.y * CH * HW;

    // ---- stage: read fp32 [c][px], write bf16 transposed [px][c] ----
    #pragma unroll
    for (int i = 0; i < 9; ++i) {
        const int f = tid + 256 * i;       // 0..2303 = c*12 + q
        const int c = f / 12;
        const int q = f - c * 12;
        if (4 * q < npx) {
            const float4 v = *(const float4*)&Xb[(size_t)c * HW + base + 4 * q];
            Xs[(4 * q + 0) * PITCH + c] = f2bf(v.x);
            Xs[(4 * q + 1) * PITCH + c] = f2bf(v.y);
            Xs[(4 * q + 2) * PITCH + c] = f2bf(v.z);
            Xs[(4 * q + 3) * PITCH + c] = f2bf(v.w);
        }
    }
    __syncthreads();

    // ---- GEMM1: m = G2 @ v ----
    f32x4 acc[3][3];
    #pragma unroll
    for (int o = 0; o < 3; ++o)
        #pragma unroll
        for (int nb = 0; nb < 3; ++nb)
            acc[o][nb] = (f32x4){0.f, 0.f, 0.f, 0.f};

    #pragma unroll
    for (int kb = 0; kb < KB; ++kb) {
        bf16x8 bfr[3];
        #pragma unroll
        for (int nb = 0; nb < 3; ++nb)
            bfr[nb] = ldsfrag(Xs, nb * 16 + lm, kb * 32 + 8 * lh);
        #pragma unroll
        for (int o = 0; o < 3; ++o) {
            bf16x8 afr = *(const bf16x8*)(g2sw + (((3 * wave + o) * KB + kb) * 64 + lane) * 8);
            #pragma unroll
            for (int nb = 0; nb < 3; ++nb)
                acc[o][nb] = __builtin_amdgcn_mfma_f32_16x16x32_bf16(afr, bfr[nb], acc[o][nb], 0, 0, 0);
        }
    }
    __syncthreads();   // GEMM1 reads of Xs done before in-place overwrite

    // ---- x = v - (m + b2); Xs <- x (bf16) in place, Qs <- x*x (bf16) ----
    #pragma unroll
    for (int o = 0; o < 3; ++o) {
        const int cb = (3 * wave + o) * 16 + 4 * lh;
        const float4 b2v = *(const float4*)(b2r + cb);
        #pragma unroll
        for (int nb = 0; nb < 3; ++nb) {
            const int n = nb * 16 + lm;
            ushort4 vv = *(const ushort4*)&Xs[n * PITCH + cb];
            float x0 = bf2f(vv.x) - (acc[o][nb][0] + b2v.x);
            float x1 = bf2f(vv.y) - (acc[o][nb][1] + b2v.y);
            float x2 = bf2f(vv.z) - (acc[o][nb][2] + b2v.z);
            float x3 = bf2f(vv.w) - (acc[o][nb][3] + b2v.w);
            ushort4 xw;
            xw.x = f2bf(x0); xw.y = f2bf(x1); xw.z = f2bf(x2); xw.w = f2bf(x3);
            *(ushort4*)&Xs[n * PITCH + cb] = xw;
            ushort4 q;
            q.x = f2bf(x0 * x0); q.y = f2bf(x1 * x1);
            q.z = f2bf(x2 * x2); q.w = f2bf(x3 * x3);
            *(ushort4*)&Qs[n * PITCH + cb] = q;
        }
    }
    __syncthreads();   // x / x^2 visible

    // ---- GEMM2: S = G1 @ (x*x), reuse acc ----
    #pragma unroll
    for (int o = 0; o < 3; ++o)
        #pragma unroll
        for (int nb = 0; nb < 3; ++nb)
            acc[o][nb] = (f32x4){0.f, 0.f, 0.f, 0.f};

    #pragma unroll
    for (int kb = 0; kb < KB; ++kb) {
        bf16x8 bfr[3];
        #pragma unroll
        for (int nb = 0; nb < 3; ++nb)
            bfr[nb] = ldsfrag(Qs, nb * 16 + lm, kb * 32 + 8 * lh);
        #pragma unroll
        for (int o = 0; o < 3; ++o) {
            bf16x8 afr = *(const bf16x8*)(g1sw + (((3 * wave + o) * KB + kb) * 64 + lane) * 8);
            #pragma unroll
            for (int nb = 0; nb < 3; ++nb)
                acc[o][nb] = __builtin_amdgcn_mfma_f32_16x16x32_bf16(afr, bfr[nb], acc[o][nb], 0, 0, 0);
        }
    }

    // ---- out = x * rsqrt(S + b1) ----
    #pragma unroll
    for (int o = 0; o < 3; ++o) {
        const int cb = (3 * wave + o) * 16 + 4 * lh;
        const float4 b1v = *(const float4*)(b1r + cb);
        #pragma unroll
        for (int nb = 0; nb < 3; ++nb) {
            const int n = nb * 16 + lm;
            if (n < npx) {
                ushort4 xv = *(const ushort4*)&Xs[n * PITCH + cb];
                float r0 = rsq(acc[o][nb][0] + b1v.x);
                float r1 = rsq(acc[o][nb][1] + b1v.y);
                float r2 = rsq(acc[o][nb][2] + b1v.z);
                float r3 = rsq(acc[o][nb][3] + b1v.w);
                Yb[(size_t)(cb + 0) * HW + base + n] = bf2f(xv.x) * r0;
                Yb[(size_t)(cb + 1) * HW + base + n] = bf2f(xv.y) * r1;
                Yb[(size_t)(cb + 2) * HW + base + n] = bf2f(xv.z) * r2;
                Yb[(size_t)(cb + 3) * HW + base + n] = bf2f(xv.w) * r3;
            }
        }
    }
}

extern "C" void kernel_launch(void* const* d_in, const int* in_sizes, int n_in,
                              void* d_out, int out_size, void* d_ws, size_t ws_size,
                              hipStream_t stream) {
    const float* X      = (const float*)d_in[0];
    const float* beta   = (const float*)d_in[1];
    const float* gamma  = (const float*)d_in[2];
    const float* beta2  = (const float*)d_in[3];
    const float* gamma2 = (const float*)d_in[4];
    float* Y = (float*)d_out;

    ushort* g2sw = (ushort*)d_ws;                 // 12*6*64*8 = 36864 elems
    ushort* g1sw = g2sw + 12 * KB * 64 * 8;
    float*  b2r  = (float*)(g1sw + 12 * KB * 64 * 8);
    float*  b1r  = b2r + CH;

    hipLaunchKernelGGL(gsdn_prep, dim3((12 * KB * 64 + 255) / 256), dim3(256), 0, stream,
                       beta, gamma, beta2, gamma2, g2sw, g1sw, b2r, b1r);
    hipLaunchKernelGGL(gsdn_main, dim3(NTPI, 4), dim3(256), 0, stream,
                       X, g2sw, g1sw, b2r, b1r, Y);
}

// Round 5
// 142.031 us; speedup vs baseline: 1.2208x; 1.0853x over previous
//
#include <hip/hip_runtime.h>
#include <cstdint>

#define CH 192
#define HW 65536
#define PN 64           // pixels per tile
#define PITCH 196       // X-tile LDS row pitch (bf16 elems, 8B-aligned b64 reads)
#define OPITCH 66       // out-tile LDS row pitch (fp32 elems, 8B-aligned b64 reads)
#define KB 6            // K blocks (192/32)
#define SMEM_BYTES 50688  // max(PN*PITCH*2 = 25088, CH*OPITCH*4 = 50688)

#define GAMMA_BOUND 3.814697265625e-06f            // 2^-18
#define PEDESTAL    1.4551915228366852e-11f        // 2^-36
#define BETA_BOUND  1.0000072759550125e-03f        // sqrt(1e-6 + 2^-36)

typedef __attribute__((ext_vector_type(8))) __bf16 bf16x8;
typedef __attribute__((ext_vector_type(4))) __bf16 bf16x4;
typedef __attribute__((ext_vector_type(4))) float  f32x4;

// native cast -> v_cvt_pk_bf16_f32 (RNE); compiler fuses pairs (m240)
__device__ __forceinline__ ushort f2bf(float f) {
    __bf16 h = (__bf16)f;
    return __builtin_bit_cast(ushort, h);
}
__device__ __forceinline__ float bf2f(ushort h) {
    union { uint32_t u; float f; } v; v.u = ((uint32_t)h) << 16;
    return v.f;
}
__device__ __forceinline__ float rsq(float x) {
    float r; asm("v_rsq_f32 %0, %1" : "=v"(r) : "v"(x)); return r;
}

// ---- prep: reparam params; store G2/G1 in MFMA-fragment order ----
// frag (o,kb) at ((o*KB+kb)*64 + lane)*8 -> A-frag loads are lane*16B contiguous.
__global__ __launch_bounds__(256) void gsdn_prep(
    const float* __restrict__ beta, const float* __restrict__ gamma,
    const float* __restrict__ beta2, const float* __restrict__ gamma2,
    ushort* __restrict__ g2sw, ushort* __restrict__ g1sw,
    float* __restrict__ b2r, float* __restrict__ b1r)
{
    int t = blockIdx.x * 256 + threadIdx.x;
    if (t < 12 * KB * 64) {
        const int o    = t / (KB * 64);
        const int r    = t - o * (KB * 64);
        const int kb   = r >> 6;
        const int lane = r & 63;
        const int row  = o * 16 + (lane & 15);
        const int col0 = kb * 32 + 8 * (lane >> 4);
        ushort w2[8], w1[8];
        #pragma unroll
        for (int j = 0; j < 8; ++j) {
            float g = fmaxf(gamma2[row * CH + col0 + j], GAMMA_BOUND);
            w2[j] = f2bf(g * g - PEDESTAL);
            float h = fmaxf(gamma[row * CH + col0 + j], GAMMA_BOUND);
            w1[j] = f2bf(h * h - PEDESTAL);
        }
        #pragma unroll
        for (int j = 0; j < 8; ++j) { g2sw[t * 8 + j] = w2[j]; g1sw[t * 8 + j] = w1[j]; }
    }
    if (t < CH) {
        float b = fmaxf(beta2[t], BETA_BOUND);
        b2r[t] = b * b - PEDESTAL;
        float a = fmaxf(beta[t], BETA_BOUND);
        b1r[t] = a * a - PEDESTAL;
    }
}

__device__ __forceinline__ bf16x8 ldsfrag(const ushort* S, int n, int k0) {
    union { bf16x8 v; struct { bf16x4 lo; bf16x4 hi; } s; } u;
    u.s.lo = *(const bf16x4*)&S[n * PITCH + k0];
    u.s.hi = *(const bf16x4*)&S[n * PITCH + k0 + 4];
    return u.v;
}

// ---- main fused kernel: 1 tile (64 px) per WG ----
__global__ __launch_bounds__(256, 3) void gsdn_main(
    const float* __restrict__ X,
    const ushort* __restrict__ g2sw, const ushort* __restrict__ g1sw,
    const float* __restrict__ b2r, const float* __restrict__ b1r,
    float* __restrict__ Y)
{
    __shared__ char smem_raw[SMEM_BYTES];
    ushort* Xs = (ushort*)smem_raw;    // v tile -> x*x tile (in place), bf16 [px][c]
    float*  Of = (float*)smem_raw;     // out tile, fp32 [c][px] (aliases Xs; Xs dead first)

    const int tid  = threadIdx.x;
    const int wave = tid >> 6;
    const int lane = tid & 63;
    const int lm   = lane & 15;
    const int lh   = lane >> 4;

    const int base = blockIdx.x * PN;
    const float* Xb = X + (size_t)blockIdx.y * CH * HW + base;
    float*       Yb = Y + (size_t)blockIdx.y * CH * HW + base;

    // ---- stage: fp32 [c][px] -> bf16 transposed [px][c] ----
    {
        const int g  = tid & 15;       // px quad (4g..4g+3)
        const int c0 = tid >> 4;       // 0..15
        #pragma unroll
        for (int j = 0; j < 12; ++j) {
            const int c = c0 + 16 * j;
            const float4 v = *(const float4*)&Xb[(size_t)c * HW + 4 * g];
            Xs[(4 * g + 0) * PITCH + c] = f2bf(v.x);
            Xs[(4 * g + 1) * PITCH + c] = f2bf(v.y);
            Xs[(4 * g + 2) * PITCH + c] = f2bf(v.z);
            Xs[(4 * g + 3) * PITCH + c] = f2bf(v.w);
        }
    }
    __syncthreads();

    // ---- GEMM1: m = G2 @ v ----
    f32x4 acc[3][4];
    #pragma unroll
    for (int o = 0; o < 3; ++o)
        #pragma unroll
        for (int nb = 0; nb < 4; ++nb)
            acc[o][nb] = (f32x4){0.f, 0.f, 0.f, 0.f};

    #pragma unroll
    for (int kb = 0; kb < KB; ++kb) {
        bf16x8 bfr[4];
        #pragma unroll
        for (int nb = 0; nb < 4; ++nb)
            bfr[nb] = ldsfrag(Xs, nb * 16 + lm, kb * 32 + 8 * lh);
        #pragma unroll
        for (int o = 0; o < 3; ++o) {
            bf16x8 afr = *(const bf16x8*)(g2sw + (((3 * wave + o) * KB + kb) * 64 + lane) * 8);
            #pragma unroll
            for (int nb = 0; nb < 4; ++nb)
                acc[o][nb] = __builtin_amdgcn_mfma_f32_16x16x32_bf16(afr, bfr[nb], acc[o][nb], 0, 0, 0);
        }
    }
    __syncthreads();   // GEMM1 reads of Xs done before in-place overwrite

    // ---- x = v - (m + b2); keep x in regs (xr); Xs <- x*x (bf16) in place ----
    f32x4 xr[3][4];
    #pragma unroll
    for (int o = 0; o < 3; ++o) {
        const int cb = (3 * wave + o) * 16 + 4 * lh;
        const float4 b2v = *(const float4*)(b2r + cb);
        #pragma unroll
        for (int nb = 0; nb < 4; ++nb) {
            const int n = nb * 16 + lm;
            ushort4 vv = *(const ushort4*)&Xs[n * PITCH + cb];
            float x0 = bf2f(vv.x) - (acc[o][nb][0] + b2v.x);
            float x1 = bf2f(vv.y) - (acc[o][nb][1] + b2v.y);
            float x2 = bf2f(vv.z) - (acc[o][nb][2] + b2v.z);
            float x3 = bf2f(vv.w) - (acc[o][nb][3] + b2v.w);
            xr[o][nb][0] = x0; xr[o][nb][1] = x1;
            xr[o][nb][2] = x2; xr[o][nb][3] = x3;
            ushort4 q;
            q.x = f2bf(x0 * x0); q.y = f2bf(x1 * x1);
            q.z = f2bf(x2 * x2); q.w = f2bf(x3 * x3);
            *(ushort4*)&Xs[n * PITCH + cb] = q;
        }
    }
    __syncthreads();   // x^2 visible

    // ---- GEMM2: S = G1 @ (x*x), reuse acc ----
    #pragma unroll
    for (int o = 0; o < 3; ++o)
        #pragma unroll
        for (int nb = 0; nb < 4; ++nb)
            acc[o][nb] = (f32x4){0.f, 0.f, 0.f, 0.f};

    #pragma unroll
    for (int kb = 0; kb < KB; ++kb) {
        bf16x8 bfr[4];
        #pragma unroll
        for (int nb = 0; nb < 4; ++nb)
            bfr[nb] = ldsfrag(Xs, nb * 16 + lm, kb * 32 + 8 * lh);
        #pragma unroll
        for (int o = 0; o < 3; ++o) {
            bf16x8 afr = *(const bf16x8*)(g1sw + (((3 * wave + o) * KB + kb) * 64 + lane) * 8);
            #pragma unroll
            for (int nb = 0; nb < 4; ++nb)
                acc[o][nb] = __builtin_amdgcn_mfma_f32_16x16x32_bf16(afr, bfr[nb], acc[o][nb], 0, 0, 0);
        }
    }
    __syncthreads();   // all GEMM2 reads of Xs done; Of may now overwrite smem

    // ---- out = x * rsqrt(S + b1) -> Of [c][px] fp32 ----
    #pragma unroll
    for (int o = 0; o < 3; ++o) {
        const int cb = (3 * wave + o) * 16 + 4 * lh;
        const float4 b1v = *(const float4*)(b1r + cb);
        #pragma unroll
        for (int nb = 0; nb < 4; ++nb) {
            const int n = nb * 16 + lm;
            Of[(cb + 0) * OPITCH + n] = xr[o][nb][0] * rsq(acc[o][nb][0] + b1v.x);
            Of[(cb + 1) * OPITCH + n] = xr[o][nb][1] * rsq(acc[o][nb][1] + b1v.y);
            Of[(cb + 2) * OPITCH + n] = xr[o][nb][2] * rsq(acc[o][nb][2] + b1v.z);
            Of[(cb + 3) * OPITCH + n] = xr[o][nb][3] * rsq(acc[o][nb][3] + b1v.w);
        }
    }
    __syncthreads();

    // ---- coalesced store: [c][px] fp32, float4 per thread-chunk ----
    #pragma unroll
    for (int i = 0; i < 12; ++i) {
        const int chunk = tid + 256 * i;     // 0..3071 = c*16 + q4
        const int c  = chunk >> 4;
        const int q4 = chunk & 15;
        const float* p = &Of[c * OPITCH + 4 * q4];
        float4 v;
        v.x = p[0]; v.y = p[1]; v.z = p[2]; v.w = p[3];
        *(float4*)&Yb[(size_t)c * HW + 4 * q4] = v;
    }
}

extern "C" void kernel_launch(void* const* d_in, const int* in_sizes, int n_in,
                              void* d_out, int out_size, void* d_ws, size_t ws_size,
                              hipStream_t stream) {
    const float* X      = (const float*)d_in[0];
    const float* beta   = (const float*)d_in[1];
    const float* gamma  = (const float*)d_in[2];
    const float* beta2  = (const float*)d_in[3];
    const float* gamma2 = (const float*)d_in[4];
    float* Y = (float*)d_out;

    ushort* g2sw = (ushort*)d_ws;                 // 12*6*64*8 = 36864 elems
    ushort* g1sw = g2sw + 12 * KB * 64 * 8;
    float*  b2r  = (float*)(g1sw + 12 * KB * 64 * 8);
    float*  b1r  = b2r + CH;

    hipLaunchKernelGGL(gsdn_prep, dim3((12 * KB * 64 + 255) / 256), dim3(256), 0, stream,
                       beta, gamma, beta2, gamma2, g2sw, g1sw, b2r, b1r);
    hipLaunchKernelGGL(gsdn_main, dim3(HW / PN, 4), dim3(256), 0, stream,
                       X, g2sw, g1sw, b2r, b1r, Y);
}

// Round 7
// 89.912 us; speedup vs baseline: 1.9284x; 1.5797x over previous
//
#include <hip/hip_runtime.h>
#include <cstdint>

#define CH 192
#define HW 65536
#define PN 64           // dense path: pixels per tile
#define PITCH 196       // dense path: X-tile LDS row pitch (bf16 elems)
#define OPITCH 66       // dense path: out-tile LDS row pitch (fp32 elems)
#define KB 6            // K blocks (192/32)
#define SMEM_BYTES 50688

#define GAMMA_BOUND 3.814697265625e-06f            // 2^-18
#define PEDESTAL    1.4551915228366852e-11f        // 2^-36
#define BETA_BOUND  1.0000072759550125e-03f        // sqrt(1e-6 + 2^-36)

typedef __attribute__((ext_vector_type(8))) __bf16 bf16x8;
typedef __attribute__((ext_vector_type(4))) __bf16 bf16x4;
typedef __attribute__((ext_vector_type(4))) float  f32x4;

__device__ __forceinline__ ushort f2bf(float f) {
    __bf16 h = (__bf16)f;
    return __builtin_bit_cast(ushort, h);
}
__device__ __forceinline__ float bf2f(ushort h) {
    union { uint32_t u; float f; } v; v.u = ((uint32_t)h) << 16;
    return v.f;
}
__device__ __forceinline__ float rsq(float x) {
    float r; asm("v_rsq_f32 %0, %1" : "=v"(r) : "v"(x)); return r;
}

// ---- kernel 0: zero the structure flag (ws not re-poisoned between replays) ----
__global__ void gsdn_flag0(unsigned* flag) { *flag = 0u; }

// ---- prep: reparam params; G2/G1 -> MFMA A-frag order (dense path);
//      diagonal + bias table (diag path); off-diagonal detection -> flag ----
__global__ __launch_bounds__(256) void gsdn_prep(
    const float* __restrict__ beta, const float* __restrict__ gamma,
    const float* __restrict__ beta2, const float* __restrict__ gamma2,
    ushort* __restrict__ g2sw, ushort* __restrict__ g1sw,
    float* __restrict__ b2r, float* __restrict__ b1r,
    float4* __restrict__ cp, unsigned* __restrict__ flag)
{
    int t = blockIdx.x * 256 + threadIdx.x;
    if (t < 12 * KB * 64) {
        const int o    = t / (KB * 64);
        const int r    = t - o * (KB * 64);
        const int kb   = r >> 6;
        const int lane = r & 63;
        const int row  = o * 16 + (lane & 15);
        const int col0 = kb * 32 + 8 * (lane >> 4);
        ushort w2[8], w1[8];
        bool nz = false;
        #pragma unroll
        for (int j = 0; j < 8; ++j) {
            float g = fmaxf(gamma2[row * CH + col0 + j], GAMMA_BOUND);
            float g2v = g * g - PEDESTAL;
            w2[j] = f2bf(g2v);
            float h = fmaxf(gamma[row * CH + col0 + j], GAMMA_BOUND);
            float g1v = h * h - PEDESTAL;
            w1[j] = f2bf(g1v);
            if (row != (col0 + j) && (g2v != 0.0f || g1v != 0.0f)) nz = true;
        }
        #pragma unroll
        for (int j = 0; j < 8; ++j) { g2sw[t * 8 + j] = w2[j]; g1sw[t * 8 + j] = w1[j]; }
        if (nz) atomicOr(flag, 1u);
    }
    if (t < CH) {
        float b = fmaxf(beta2[t], BETA_BOUND);
        float b2 = b * b - PEDESTAL;
        float a = fmaxf(beta[t], BETA_BOUND);
        float b1 = a * a - PEDESTAL;
        b2r[t] = b2;
        b1r[t] = b1;
        float gd = fmaxf(gamma2[t * CH + t], GAMMA_BOUND);
        float d2 = gd * gd - PEDESTAL;
        float hd = fmaxf(gamma[t * CH + t], GAMMA_BOUND);
        float d1 = hd * hd - PEDESTAL;
        float4 p;
        p.x = 1.0f - d2;   // x = p.x*v - b2
        p.y = b2;
        p.z = d1;          // out = x*rsqrt(d1*x^2 + b1)
        p.w = b1;
        cp[t] = p;
    }
}

// ---- diagonal fast path: pure elementwise, fp32, memory-bound ----
// grid: 4 img * 192 ch * 4 quarter-planes = 3072 blocks; runs iff flag==0.
__global__ __launch_bounds__(256) void gsdn_diag(
    const float* __restrict__ X, const float4* __restrict__ cp,
    const unsigned* __restrict__ flag, float* __restrict__ Y)
{
    if (*flag != 0u) return;
    const int b   = blockIdx.x;
    const int img = b >> 9;          // 512 blocks per image? no: 768. use div below
    const int r   = b - (b / 768) * 768;
    const int im  = b / 768;
    const int c   = r >> 2;
    const int q   = r & 3;
    (void)img;
    const float4 p = cp[c];
    const size_t base = ((size_t)im * CH + c) * (HW / 4) + (size_t)q * 4096 + threadIdx.x;
    const float4* xp = (const float4*)X + base;
    float4*       yp = (float4*)Y + base;
    #pragma unroll
    for (int k = 0; k < 16; ++k) {
        float4 v = xp[k * 256];
        float4 o;
        float x0 = p.x * v.x - p.y;
        float x1 = p.x * v.y - p.y;
        float x2 = p.x * v.z - p.y;
        float x3 = p.x * v.w - p.y;
        o.x = x0 * rsq(p.z * x0 * x0 + p.w);
        o.y = x1 * rsq(p.z * x1 * x1 + p.w);
        o.z = x2 * rsq(p.z * x2 * x2 + p.w);
        o.w = x3 * rsq(p.z * x3 * x3 + p.w);
        yp[k * 256] = o;
    }
}

__device__ __forceinline__ bf16x8 ldsfrag(const ushort* S, int n, int k0) {
    union { bf16x8 v; struct { bf16x4 lo; bf16x4 hi; } s; } u;
    u.s.lo = *(const bf16x4*)&S[n * PITCH + k0];
    u.s.hi = *(const bf16x4*)&S[n * PITCH + k0 + 4];
    return u.v;
}

// ---- dense fallback (r5-verified MFMA kernel); runs iff flag!=0 ----
__global__ __launch_bounds__(256, 3) void gsdn_main(
    const float* __restrict__ X,
    const ushort* __restrict__ g2sw, const ushort* __restrict__ g1sw,
    const float* __restrict__ b2r, const float* __restrict__ b1r,
    const unsigned* __restrict__ flag, float* __restrict__ Y)
{
    if (*flag == 0u) return;
    __shared__ char smem_raw[SMEM_BYTES];
    ushort* Xs = (ushort*)smem_raw;
    float*  Of = (float*)smem_raw;

    const int tid  = threadIdx.x;
    const int wave = tid >> 6;
    const int lane = tid & 63;
    const int lm   = lane & 15;
    const int lh   = lane >> 4;

    const int base = blockIdx.x * PN;
    const float* Xb = X + (size_t)blockIdx.y * CH * HW + base;
    float*       Yb = Y + (size_t)blockIdx.y * CH * HW + base;

    {
        const int g  = tid & 15;
        const int c0 = tid >> 4;
        #pragma unroll
        for (int j = 0; j < 12; ++j) {
            const int c = c0 + 16 * j;
            const float4 v = *(const float4*)&Xb[(size_t)c * HW + 4 * g];
            Xs[(4 * g + 0) * PITCH + c] = f2bf(v.x);
            Xs[(4 * g + 1) * PITCH + c] = f2bf(v.y);
            Xs[(4 * g + 2) * PITCH + c] = f2bf(v.z);
            Xs[(4 * g + 3) * PITCH + c] = f2bf(v.w);
        }
    }
    __syncthreads();

    f32x4 acc[3][4];
    #pragma unroll
    for (int o = 0; o < 3; ++o)
        #pragma unroll
        for (int nb = 0; nb < 4; ++nb)
            acc[o][nb] = (f32x4){0.f, 0.f, 0.f, 0.f};

    #pragma unroll
    for (int kb = 0; kb < KB; ++kb) {
        bf16x8 bfr[4];
        #pragma unroll
        for (int nb = 0; nb < 4; ++nb)
            bfr[nb] = ldsfrag(Xs, nb * 16 + lm, kb * 32 + 8 * lh);
        #pragma unroll
        for (int o = 0; o < 3; ++o) {
            bf16x8 afr = *(const bf16x8*)(g2sw + (((3 * wave + o) * KB + kb) * 64 + lane) * 8);
            #pragma unroll
            for (int nb = 0; nb < 4; ++nb)
                acc[o][nb] = __builtin_amdgcn_mfma_f32_16x16x32_bf16(afr, bfr[nb], acc[o][nb], 0, 0, 0);
        }
    }
    __syncthreads();

    f32x4 xr[3][4];
    #pragma unroll
    for (int o = 0; o < 3; ++o) {
        const int cb = (3 * wave + o) * 16 + 4 * lh;
        const float4 b2v = *(const float4*)(b2r + cb);
        #pragma unroll
        for (int nb = 0; nb < 4; ++nb) {
            const int n = nb * 16 + lm;
            ushort4 vv = *(const ushort4*)&Xs[n * PITCH + cb];
            float x0 = bf2f(vv.x) - (acc[o][nb][0] + b2v.x);
            float x1 = bf2f(vv.y) - (acc[o][nb][1] + b2v.y);
            float x2 = bf2f(vv.z) - (acc[o][nb][2] + b2v.z);
            float x3 = bf2f(vv.w) - (acc[o][nb][3] + b2v.w);
            xr[o][nb][0] = x0; xr[o][nb][1] = x1;
            xr[o][nb][2] = x2; xr[o][nb][3] = x3;
            ushort4 q;
            q.x = f2bf(x0 * x0); q.y = f2bf(x1 * x1);
            q.z = f2bf(x2 * x2); q.w = f2bf(x3 * x3);
            *(ushort4*)&Xs[n * PITCH + cb] = q;
        }
    }
    __syncthreads();

    #pragma unroll
    for (int o = 0; o < 3; ++o)
        #pragma unroll
        for (int nb = 0; nb < 4; ++nb)
            acc[o][nb] = (f32x4){0.f, 0.f, 0.f, 0.f};

    #pragma unroll
    for (int kb = 0; kb < KB; ++kb) {
        bf16x8 bfr[4];
        #pragma unroll
        for (int nb = 0; nb < 4; ++nb)
            bfr[nb] = ldsfrag(Xs, nb * 16 + lm, kb * 32 + 8 * lh);
        #pragma unroll
        for (int o = 0; o < 3; ++o) {
            bf16x8 afr = *(const bf16x8*)(g1sw + (((3 * wave + o) * KB + kb) * 64 + lane) * 8);
            #pragma unroll
            for (int nb = 0; nb < 4; ++nb)
                acc[o][nb] = __builtin_amdgcn_mfma_f32_16x16x32_bf16(afr, bfr[nb], acc[o][nb], 0, 0, 0);
        }
    }
    __syncthreads();

    #pragma unroll
    for (int o = 0; o < 3; ++o) {
        const int cb = (3 * wave + o) * 16 + 4 * lh;
        const float4 b1v = *(const float4*)(b1r + cb);
        #pragma unroll
        for (int nb = 0; nb < 4; ++nb) {
            const int n = nb * 16 + lm;
            Of[(cb + 0) * OPITCH + n] = xr[o][nb][0] * rsq(acc[o][nb][0] + b1v.x);
            Of[(cb + 1) * OPITCH + n] = xr[o][nb][1] * rsq(acc[o][nb][1] + b1v.y);
            Of[(cb + 2) * OPITCH + n] = xr[o][nb][2] * rsq(acc[o][nb][2] + b1v.z);
            Of[(cb + 3) * OPITCH + n] = xr[o][nb][3] * rsq(acc[o][nb][3] + b1v.w);
        }
    }
    __syncthreads();

    #pragma unroll
    for (int i = 0; i < 12; ++i) {
        const int chunk = tid + 256 * i;
        const int c  = chunk >> 4;
        const int q4 = chunk & 15;
        const float* p = &Of[c * OPITCH + 4 * q4];
        float4 v;
        v.x = p[0]; v.y = p[1]; v.z = p[2]; v.w = p[3];
        *(float4*)&Yb[(size_t)c * HW + 4 * q4] = v;
    }
}

extern "C" void kernel_launch(void* const* d_in, const int* in_sizes, int n_in,
                              void* d_out, int out_size, void* d_ws, size_t ws_size,
                              hipStream_t stream) {
    const float* X      = (const float*)d_in[0];
    const float* beta   = (const float*)d_in[1];
    const float* gamma  = (const float*)d_in[2];
    const float* beta2  = (const float*)d_in[3];
    const float* gamma2 = (const float*)d_in[4];
    float* Y = (float*)d_out;

    char* ws = (char*)d_ws;
    float4*   cp   = (float4*)(ws + 0);          // 3072 B
    float*    b2r  = (float*)(ws + 3072);        // 768
    float*    b1r  = (float*)(ws + 3840);        // 768
    unsigned* flag = (unsigned*)(ws + 4608);     // 4 (+pad)
    ushort*   g2sw = (ushort*)(ws + 4624);       // 73728
    ushort*   g1sw = (ushort*)(ws + 78352);      // 73728

    hipLaunchKernelGGL(gsdn_flag0, dim3(1), dim3(1), 0, stream, flag);
    hipLaunchKernelGGL(gsdn_prep, dim3((12 * KB * 64 + 255) / 256), dim3(256), 0, stream,
                       beta, gamma, beta2, gamma2, g2sw, g1sw, b2r, b1r, cp, flag);
    hipLaunchKernelGGL(gsdn_diag, dim3(4 * CH * 4), dim3(256), 0, stream,
                       X, cp, flag, Y);
    hipLaunchKernelGGL(gsdn_main, dim3(HW / PN, 4), dim3(256), 0, stream,
                       X, g2sw, g1sw, b2r, b1r, flag, Y);
}